// Round 6
// baseline (283.149 us; speedup 1.0000x reference)
//
#include <hip/hip_runtime.h>

namespace {
constexpr int S_LEN = 512;
constexpr int BATCH = 1024;
constexpr int TAG = 64;
constexpr int START_IDX = 0;
constexpr int END_IDX = 1;
constexpr float NEG_INF = -10000.0f;
constexpr int CHUNK = 64;              // steps per LDS feat chunk (16 KB)
constexpr float LN2F = 0.69314718055994530942f;

typedef float v4f __attribute__((ext_vector_type(4)));

typedef const __attribute__((address_space(1))) void* gas_ptr;
typedef __attribute__((address_space(3))) void* las_ptr;

__device__ inline void gld_lds16(const float* g, float* l) {
  // LDS dest = wave-uniform base + lane*16 (hardware); global src is per-lane.
  __builtin_amdgcn_global_load_lds((gas_ptr)(const void*)g, (las_ptr)(void*)l, 16, 0, 0);
}

template <int CTRL>
__device__ __forceinline__ unsigned dppmov(unsigned v) {
  return (unsigned)__builtin_amdgcn_mov_dpp((int)v, CTRL, 0xF, 0xF, false);
}

__device__ __forceinline__ unsigned swz_x16(unsigned v) {
  // ds_swizzle BitMode: xor_mask=16, and_mask=0x1F -> lane ^ 16
  return (unsigned)__builtin_amdgcn_ds_swizzle((int)v, 0x401F);
}

// In-register all-gather: u[0..63] = the wave's 64 per-lane values of x.
// Slot r of lane l holds x from lane g_r(l); the mapping is whatever the network
// does — captured exactly by running the SAME network on the lane index itself.
// Stages (each doubles coverage with disjoint blocks):
//   ^32: ds_bpermute   ^16: ds_swizzle   ±8, ±4: DPP row_ror   ^2, ^1: DPP quad_perm
// 3 DS ops total, at subtree roots (latency hides under the other subtree's DPP/FMA).
__device__ __forceinline__ void allgather64(unsigned x, int lane, unsigned u[64]) {
  u[0]  = x;
  u[32] = (unsigned)__builtin_amdgcn_ds_bpermute((lane ^ 32) << 2, (int)x);
  u[16] = swz_x16(u[0]);
  u[48] = swz_x16(u[32]);
#pragma unroll
  for (int h = 0; h < 64; h += 16) u[h + 8] = dppmov<0x128>(u[h]);  // row_ror:8
#pragma unroll
  for (int h = 0; h < 64; h += 8)  u[h + 4] = dppmov<0x124>(u[h]);  // row_ror:4
#pragma unroll
  for (int h = 0; h < 64; h += 4)  u[h + 2] = dppmov<0x4E>(u[h]);   // quad_perm xor2
#pragma unroll
  for (int h = 0; h < 64; h += 2)  u[h + 1] = dppmov<0xB1>(u[h]);   // quad_perm xor1
}
}

// One wave (64 lanes) per batch; lane = destination tag j.
// Linear-domain recurrence: p_j = exp(alpha_j - etot*ln2), exact power-of-2 renorm
// from exponent bits of lane 2's p (wave-uniform).
//   t_j = sum_r  p[g_r] * E[j, g_r]      (all-gather in registers, NO LDS round-trip)
//   p'  = t * exp(feat) * 2^-e
// E is loaded pre-permuted per slot (Eg[r] = exp(trans[j, g_r])) using the index
// simulation, so the slot order cancels. The serial chain is pure VALU issue.
// Feats staged 64 steps ahead into double-buffered LDS via global_load_lds;
// mask collapsed to L = sum(mask) once at entry (mask monotone in s).
__global__ __launch_bounds__(64, 1) void crf_fwd_kernel(
    const float* __restrict__ feats,   // [S, B, T]
    const float* __restrict__ mask,    // [S, B]
    const float* __restrict__ trans,   // [T, T]
    float* __restrict__ out) {         // [B]
  const int b = blockIdx.x;
  const int lane = threadIdx.x;  // tag j

  __shared__ __align__(16) float fchunk[2][CHUNK * TAG];  // 2 x 16 KB

  // ---- effective length L = sum_s mask[s,b] (mask monotone non-increasing) ----
  int L;
  {
    float sum = 0.0f;
#pragma unroll
    for (int k = 0; k < S_LEN / 64; ++k) sum += mask[(size_t)(lane + 64 * k) * BATCH + b];
#pragma unroll
    for (int off = 32; off >= 1; off >>= 1) sum += __shfl_xor(sum, off, 64);
    L = (int)(sum + 0.5f);
  }

  // ---- index simulation: slot r <- source lane g_r; then E pre-permuted ----
  float Eg[64];
  {
    unsigned gi[64];
    allgather64((unsigned)lane, lane, gi);
    const float* trow = trans + lane * TAG;
#pragma unroll
    for (int r = 0; r < 64; ++r) Eg[r] = __expf(trow[gi[r]]);  // exp(-1e4) -> 0
  }

  // per-lane invariant staging address: one gld_lds16 moves 4 rows (4 x 256 B)
  const float* gstage0 =
      feats + ((size_t)(lane >> 4) * BATCH + b) * TAG + ((lane & 15) << 2);

  auto stage_chunk = [&](int base_s, int nb) {
    const float* g0 = gstage0 + (size_t)base_s * (BATCH * TAG);
#pragma unroll
    for (int q = 0; q < 16; ++q) {
      gld_lds16(g0 + (size_t)(4 * q) * (BATCH * TAG), &fchunk[nb][q * 256]);
    }
  };

  float p = (lane == START_IDX) ? 1.0f : 0.0f;
  int etot = 0;  // running power-of-2 count: M = etot * ln2 (exact scaling)

  // ---- prologue: stage chunk 0 and wait for it ----
  stage_chunk(0, 0);
  asm volatile("s_waitcnt vmcnt(0)" ::: "memory");
  __builtin_amdgcn_sched_barrier(0);
  __builtin_amdgcn_wave_barrier();

  // one step: all-gather (63 shuffle ops, 3 on DS pipe) + 64 fmac + tree + mul
  auto step = [&](float ex) {
    const unsigned pu = __float_as_uint(p);

    unsigned u[64];
    allgather64(pu, lane, u);

    // renorm (wave-uniform; readlane+SALU overlap the shuffle/FMA stream)
    const unsigned pb = __builtin_amdgcn_readlane(pu, 2);
    const unsigned eb = (pb == 0u) ? 127u : (pb >> 23);
    etot += (int)eb - 127;
    const float cg = ex * __uint_as_float((254u - eb) << 23);  // * 2^(127-eb), exact

    float a0 = 0.f, a1 = 0.f, a2 = 0.f, a3 = 0.f;
    float a4 = 0.f, a5 = 0.f, a6 = 0.f, a7 = 0.f;
#pragma unroll
    for (int r = 0; r < 64; r += 8) {
      a0 = __builtin_fmaf(__uint_as_float(u[r + 0]), Eg[r + 0], a0);
      a1 = __builtin_fmaf(__uint_as_float(u[r + 1]), Eg[r + 1], a1);
      a2 = __builtin_fmaf(__uint_as_float(u[r + 2]), Eg[r + 2], a2);
      a3 = __builtin_fmaf(__uint_as_float(u[r + 3]), Eg[r + 3], a3);
      a4 = __builtin_fmaf(__uint_as_float(u[r + 4]), Eg[r + 4], a4);
      a5 = __builtin_fmaf(__uint_as_float(u[r + 5]), Eg[r + 5], a5);
      a6 = __builtin_fmaf(__uint_as_float(u[r + 6]), Eg[r + 6], a6);
      a7 = __builtin_fmaf(__uint_as_float(u[r + 7]), Eg[r + 7], a7);
    }
    const float t = ((a0 + a1) + (a2 + a3)) + ((a4 + a5) + (a6 + a7));
    p = t * cg;  // single on-chain multiply
  };

  for (int c = 0;; ++c) {
    const int base = c * CHUNK;
    int n = L - base;
    if (n <= 0) break;
    if (n > CHUNK) n = CHUNK;

    const int nbase = base + CHUNK;
    if (nbase < S_LEN) stage_chunk(nbase, (c + 1) & 1);  // async, 64 steps ahead

    const float* fb = &fchunk[c & 1][0];

    // 8-step groups: feat reads + exp batched off-chain (DS pipe is idle now)
    auto group8 = [&](int s0) {
      float ex[8];
#pragma unroll
      for (int i = 0; i < 8; ++i) ex[i] = fb[(s0 + i) * TAG + lane];
#pragma unroll
      for (int i = 0; i < 8; ++i) ex[i] = __expf(ex[i]);
#pragma unroll
      for (int i = 0; i < 8; ++i) step(ex[i]);
    };

    if (n == CHUNK) {
      for (int g = 0; g < CHUNK / 8; ++g) group8(8 * g);
    } else {
      const int full = n >> 3;
      for (int g = 0; g < full; ++g) group8(8 * g);
      for (int i = full * 8; i < n; ++i) {  // tail (rare): on-chain exp is fine here
        step(__expf(fb[i * TAG + lane]));
      }
      break;  // L reached inside this chunk
    }

    if (nbase >= L) break;  // done; skip the drain

    // next chunk's loads were issued 64 steps ago: drain is ~free
    asm volatile("s_waitcnt vmcnt(0)" ::: "memory");
    __builtin_amdgcn_sched_barrier(0);
    __builtin_amdgcn_wave_barrier();
  }

  // drain any in-flight staging before LDS is deallocated at wave exit
  asm volatile("s_waitcnt vmcnt(0)" ::: "memory");

  // ---- epilogue: out[b] = logsumexp_j(etot*ln2 + log p_j + trans[END, j]) ----
  {
    const float a = (float)etot * LN2F + __logf(p) + trans[END_IDX * TAG + lane];
    float mx = a;  // p==0 -> a=-inf; lane 2 always finite so mx finite
#pragma unroll
    for (int off = 32; off >= 1; off >>= 1) mx = fmaxf(mx, __shfl_xor(mx, off, 64));
    float e = __expf(a - mx);
#pragma unroll
    for (int off = 32; off >= 1; off >>= 1) e += __shfl_xor(e, off, 64);
    if (lane == 0) out[b] = mx + __logf(e);
  }
}

extern "C" void kernel_launch(void* const* d_in, const int* in_sizes, int n_in,
                              void* d_out, int out_size, void* d_ws, size_t ws_size,
                              hipStream_t stream) {
  const float* feats = (const float*)d_in[0];
  const float* mask = (const float*)d_in[1];
  const float* trans = (const float*)d_in[2];
  float* out = (float*)d_out;
  crf_fwd_kernel<<<dim3(BATCH), dim3(64), 0, stream>>>(feats, mask, trans, out);
}

// Round 7
// 268.881 us; speedup vs baseline: 1.0531x; 1.0531x over previous
//
#include <hip/hip_runtime.h>

namespace {
constexpr int S_LEN = 512;
constexpr int BATCH = 1024;
constexpr int TAG = 64;
constexpr int START_IDX = 0;
constexpr int END_IDX = 1;
constexpr int CHUNK = 64;              // steps per LDS feat chunk (16 KB)
constexpr float LN2F = 0.69314718055994530942f;

typedef float v2f __attribute__((ext_vector_type(2)));
typedef float v4f __attribute__((ext_vector_type(4)));

typedef const __attribute__((address_space(1))) void* gas_ptr;
typedef __attribute__((address_space(3))) void* las_ptr;

__device__ inline void gld_lds16(const float* g, float* l) {
  // LDS dest = wave-uniform base + lane*16 (hardware); global src is per-lane.
  __builtin_amdgcn_global_load_lds((gas_ptr)(const void*)g, (las_ptr)(void*)l, 16, 0, 0);
}

template <int CTRL>
__device__ __forceinline__ float qswap(float v) {
  // quad_perm DPP (within-quad permutation); validated in round 6's kernel.
  return __uint_as_float((unsigned)__builtin_amdgcn_mov_dpp(
      (int)__float_as_uint(v), CTRL, 0xF, 0xF, false));
}
}

// One wave (64 lanes) per batch. Work split to cut DS-pipe traffic 3x (the
// measured bottleneck: 4 waves/CU share one DS pipe; full-broadcast reads moved
// 16.5 KB/step/wave over the 256 B/clk return bus):
//   lane l: output rows 4q..4q+3 (q = l>>2), input chunk c = l&3 (i in [16c,16c+16))
//   per step: 4x ds_read_b128 (own 16 p-values) -> 32 pk_fma (4 rows x 16 inputs)
//             -> quad butterfly (DPP xor1/xor2) sums the 4 chunk-partials
//             -> p'[4q..4q+3] = t * cg, one ds_write_b128 (contiguous rows)
// Linear-domain recurrence with exact power-of-2 renorm (anchor = row 2, which is
// lane 0's m=2 component; one off-chain readlane). Feats staged 64 steps ahead in
// double-buffered LDS; mask collapsed to L = sum(mask) once (monotone in s).
__global__ __launch_bounds__(64, 1) void crf_fwd_kernel(
    const float* __restrict__ feats,   // [S, B, T]
    const float* __restrict__ mask,    // [S, B]
    const float* __restrict__ trans,   // [T, T]
    float* __restrict__ out) {         // [B]
  const int b = blockIdx.x;
  const int lane = threadIdx.x;
  const int q = lane >> 2;   // row group: rows 4q..4q+3
  const int c = lane & 3;    // input chunk: i in [16c, 16c+16)

  __shared__ __align__(16) float fchunk[2][CHUNK * TAG];  // 2 x 16 KB
  __shared__ __align__(16) float p_lds[TAG];              // p in natural order

  // ---- effective length L = sum_s mask[s,b] (mask monotone non-increasing) ----
  int L;
  {
    float sum = 0.0f;
#pragma unroll
    for (int k = 0; k < S_LEN / 64; ++k) sum += mask[(size_t)(lane + 64 * k) * BATCH + b];
#pragma unroll
    for (int off = 32; off >= 1; off >>= 1) sum += __shfl_xor(sum, off, 64);
    L = (int)(sum + 0.5f);
  }

  // ---- one-time: E fragments. El[m][k]: rows 4q+m, chunk c, as 8 v2f per row ----
  v2f El[4][8];
#pragma unroll
  for (int m = 0; m < 4; ++m) {
    const float* row = trans + (size_t)(4 * q + m) * TAG + 16 * c;
#pragma unroll
    for (int k = 0; k < 4; ++k) {
      v4f tv;
      __builtin_memcpy(&tv, row + 4 * k, sizeof(v4f));
      El[m][2 * k]     = v2f{__expf(tv.x), __expf(tv.y)};  // exp(-10000) -> 0
      El[m][2 * k + 1] = v2f{__expf(tv.z), __expf(tv.w)};
    }
  }

  // per-lane invariant staging address: one gld_lds16 moves 4 rows (4 x 256 B)
  const float* gstage0 =
      feats + ((size_t)(lane >> 4) * BATCH + b) * TAG + ((lane & 15) << 2);

  auto stage_chunk = [&](int base_s, int nb) {
    const float* g0 = gstage0 + (size_t)base_s * (BATCH * TAG);
#pragma unroll
    for (int t = 0; t < 16; ++t) {
      gld_lds16(g0 + (size_t)(4 * t) * (BATCH * TAG), &fchunk[nb][t * 256]);
    }
  };

  // ---- initial state: p = e_START in LDS; pm registers mirror rows 4q..4q+3 ----
  p_lds[lane] = (lane == START_IDX) ? 1.0f : 0.0f;
  __builtin_amdgcn_wave_barrier();
  float pm0 = (q == 0) ? 1.0f : 0.0f, pm1 = 0.0f, pm2 = 0.0f, pm3 = 0.0f;
  int etot = 0;  // running power-of-2 count: M = etot * ln2 (exact scaling)

  // ---- prologue: stage chunk 0 and wait for it ----
  stage_chunk(0, 0);
  asm volatile("s_waitcnt vmcnt(0)" ::: "memory");
  __builtin_amdgcn_sched_barrier(0);
  __builtin_amdgcn_wave_barrier();

  // one step; cgv = exp(feat[s, 4q..4q+3]) (computed off-chain)
  auto step = [&](const v4f& cgv) {
    // anchor renorm from previous p (row 2 = lane 0's pm2); off the DS chain
    const unsigned pb = __builtin_amdgcn_readlane(__float_as_uint(pm2), 0);
    const unsigned eb = (pb == 0u) ? 127u : (pb >> 23);
    etot += (int)eb - 127;
    const float scale = __uint_as_float((254u - eb) << 23);  // 2^(127-eb), exact
    const float cg0 = cgv.x * scale, cg1 = cgv.y * scale;
    const float cg2 = cgv.z * scale, cg3 = cgv.w * scale;

    // head: read own 16 p-values (4 x b128; 4 address groups, 2-way banks = free)
    const float* pl = p_lds + 16 * c;
    v4f r0, r1, r2, r3;
    __builtin_memcpy(&r0, pl + 0,  sizeof(v4f));
    __builtin_memcpy(&r1, pl + 4,  sizeof(v4f));
    __builtin_memcpy(&r2, pl + 8,  sizeof(v4f));
    __builtin_memcpy(&r3, pl + 12, sizeof(v4f));
    const v2f pv0 = {r0.x, r0.y}, pv1 = {r0.z, r0.w};
    const v2f pv2 = {r1.x, r1.y}, pv3 = {r1.z, r1.w};
    const v2f pv4 = {r2.x, r2.y}, pv5 = {r2.z, r2.w};
    const v2f pv6 = {r3.x, r3.y}, pv7 = {r3.z, r3.w};

    // 4 row-partials over this lane's 16-input chunk (2 v2f chains per row)
    float s0, s1, s2, s3;
#pragma unroll
    for (int m = 0; m < 4; ++m) {
      v2f a = pv0 * El[m][0];
      v2f d = pv1 * El[m][1];
      a += pv2 * El[m][2];
      d += pv3 * El[m][3];
      a += pv4 * El[m][4];
      d += pv5 * El[m][5];
      a += pv6 * El[m][6];
      d += pv7 * El[m][7];
      const v2f t = a + d;
      const float sm = t.x + t.y;
      if (m == 0) s0 = sm; else if (m == 1) s1 = sm; else if (m == 2) s2 = sm; else s3 = sm;
    }

    // quad butterfly: sum the 4 chunk-partials (all quad lanes end with full sums)
    s0 += qswap<0xB1>(s0);  // xor1
    s1 += qswap<0xB1>(s1);
    s2 += qswap<0xB1>(s2);
    s3 += qswap<0xB1>(s3);
    s0 += qswap<0x4E>(s0);  // xor2
    s1 += qswap<0x4E>(s1);
    s2 += qswap<0x4E>(s2);
    s3 += qswap<0x4E>(s3);

    pm0 = s0 * cg0;
    pm1 = s1 * cg1;
    pm2 = s2 * cg2;
    pm3 = s3 * cg3;

    __builtin_amdgcn_wave_barrier();  // write stays after this step's reads
    const v4f pw = {pm0, pm1, pm2, pm3};
    __builtin_memcpy(&p_lds[4 * q], &pw, sizeof(v4f));  // rows 4q..4q+3, one b128
    __builtin_amdgcn_wave_barrier();  // next step's reads stay after the write
  };

  auto exp4 = [](v4f v) -> v4f {
    return v4f{__expf(v.x), __expf(v.y), __expf(v.z), __expf(v.w)};
  };

  for (int ch = 0;; ++ch) {
    const int base = ch * CHUNK;
    int n = L - base;
    if (n <= 0) break;
    if (n > CHUNK) n = CHUNK;

    const int nbase = base + CHUNK;
    if (nbase < S_LEN) stage_chunk(nbase, (ch + 1) & 1);  // async, 64 steps ahead

    const float* fb = &fchunk[ch & 1][0];

    // 4-step groups: cg reads (1 b128/step) + exp batched off-chain
    auto group4 = [&](int s0g) {
      v4f cg[4];
#pragma unroll
      for (int i = 0; i < 4; ++i)
        __builtin_memcpy(&cg[i], fb + (s0g + i) * TAG + 4 * q, sizeof(v4f));
#pragma unroll
      for (int i = 0; i < 4; ++i) cg[i] = exp4(cg[i]);
#pragma unroll
      for (int i = 0; i < 4; ++i) step(cg[i]);
    };

    if (n == CHUNK) {
      for (int g = 0; g < CHUNK / 4; ++g) group4(4 * g);
    } else {
      const int full = n >> 2;
      for (int g = 0; g < full; ++g) group4(4 * g);
      for (int i = full * 4; i < n; ++i) {  // tail (rare)
        v4f cg;
        __builtin_memcpy(&cg, fb + i * TAG + 4 * q, sizeof(v4f));
        step(exp4(cg));
      }
      break;  // L reached inside this chunk
    }

    if (nbase >= L) break;  // done; skip the drain

    // next chunk's loads were issued 64 steps ago: drain is ~free
    asm volatile("s_waitcnt vmcnt(0)" ::: "memory");
    __builtin_amdgcn_sched_barrier(0);
    __builtin_amdgcn_wave_barrier();
  }

  // drain any in-flight staging before LDS is deallocated at wave exit
  asm volatile("s_waitcnt vmcnt(0)" ::: "memory");

  // ---- epilogue: p_lds already holds final p (natural order) ----
  {
    __builtin_amdgcn_wave_barrier();
    const float pj = p_lds[lane];
    const float a = (float)etot * LN2F + __logf(pj) + trans[END_IDX * TAG + lane];
    float mx = a;  // pj==0 -> a=-inf; row 2 finite so mx finite
#pragma unroll
    for (int off = 32; off >= 1; off >>= 1) mx = fmaxf(mx, __shfl_xor(mx, off, 64));
    float e = __expf(a - mx);
#pragma unroll
    for (int off = 32; off >= 1; off >>= 1) e += __shfl_xor(e, off, 64);
    if (lane == 0) out[b] = mx + __logf(e);
  }
}

extern "C" void kernel_launch(void* const* d_in, const int* in_sizes, int n_in,
                              void* d_out, int out_size, void* d_ws, size_t ws_size,
                              hipStream_t stream) {
  const float* feats = (const float*)d_in[0];
  const float* mask = (const float*)d_in[1];
  const float* trans = (const float*)d_in[2];
  float* out = (float*)d_out;
  crf_fwd_kernel<<<dim3(BATCH), dim3(64), 0, stream>>>(feats, mask, trans, out);
}